// Round 6
// baseline (415.287 us; speedup 1.0000x reference)
//
#include <hip/hip_runtime.h>

#define BATCH   128
#define NUM_IN  4096
#define LVL     8
#define HID     32768
#define KH      32
#define OUTN    256
#define KOUT    64
#define SCALEA  4.9f
#define INV255  (1.0f / 255.0f)
#define ZIN     NUM_IN        // zeroed dummy input node
#define ZHID    (LVL * HID)   // zeroed dummy hidden node (hidden-relative)

// Workspace layout:
//   in_f @ 0         : f32 inputs node-major in_f[n*128+b], n in [0,4096]
//                      (node 4096 = zero dummy)                  2.10 MB
//   hid  @ 2,097,664 : u8 hidden acts node-major, node stride 128 B
//                      (64 ushorts/node, lane = batch pair);
//                      node ZHID = zero dummy                    33.55 MB
//
// R5 post-mortem: prep_hidden (46 us) was the largest dispatch. Eliminated:
// each entry now does TWO unconditional gathers with scalar-select addresses
// (wrong-type gather lands on a zeroed dummy node -> contributes 0). No
// control flow between loads (the R4 killer), no prep round-trip.

__global__ __launch_bounds__(256) void transpose_x(const float* __restrict__ x,
                                                   float* __restrict__ in_f,
                                                   unsigned short* __restrict__ hid) {
    __shared__ float lds[64][129];
    const int n0 = blockIdx.x * 64;
    const int t  = threadIdx.x;
    #pragma unroll
    for (int it = 0; it < 32; ++it) {
        int i = it * 256 + t;
        int b = i >> 6;
        int n = i & 63;
        lds[n][b] = x[b * NUM_IN + n0 + n];
    }
    __syncthreads();
    #pragma unroll
    for (int it = 0; it < 32; ++it) {
        int i = it * 256 + t;
        int n = i >> 7;
        int b = i & 127;
        in_f[(n0 + n) * BATCH + b] = lds[n][b];
    }
    if (blockIdx.x == 0) {
        if (t < BATCH) in_f[(unsigned)ZIN * BATCH + t] = 0.f;   // zero dummy input
        if (t < 64)    hid[(unsigned)ZHID * 64 + t]    = 0;     // zero dummy hidden
    }
}

// Level 0: all sources are inputs (randint maxval = NUM_IN). f32-only gathers.
__global__ __launch_bounds__(256) void level0(const float* __restrict__ in_f,
                                              unsigned short* __restrict__ hid,
                                              const int* __restrict__ idx,
                                              const float* __restrict__ w) {
    const int lane = threadIdx.x & 63;
    int h = (blockIdx.x << 2) + (threadIdx.x >> 6);
    h = __builtin_amdgcn_readfirstlane(h);
    const int*   ip = idx + h * KH;
    const float* wp = w   + h * KH;
    float ax = 0.f, ay = 0.f;
    #pragma unroll
    for (int k = 0; k < KH; ++k) {
        int   j  = __builtin_amdgcn_readfirstlane(ip[k]);
        float wk = wp[k];
        const float2 v = *(const float2*)(in_f + (unsigned)j * BATCH + 2 * lane);
        ax = fmaf(wk, v.x, ax);
        ay = fmaf(wk, v.y, ay);
    }
    unsigned qx = __float2uint_rn(255.f / (1.f + __expf(-SCALEA * ax)));
    unsigned qy = __float2uint_rn(255.f / (1.f + __expf(-SCALEA * ay)));
    hid[(unsigned)h * 64 + lane] = (unsigned short)(qx | (qy << 8));
}

// Levels 1..7: per entry, dual unconditional gather with scalar-select
// addresses. Input entry -> real f32 + dummy u8(=0); hidden entry ->
// dummy f32(=0, L1-resident line) + real u8. Branchless, loads batchable.
__global__ __launch_bounds__(256) void deep_level(const float* __restrict__ in_f,
                                                  unsigned short* __restrict__ hid,
                                                  const int* __restrict__ idx,
                                                  const float* __restrict__ w,
                                                  int hbase) {
    const int lane = threadIdx.x & 63;
    int h = (blockIdx.x << 2) + (threadIdx.x >> 6);
    h = __builtin_amdgcn_readfirstlane(h);
    const int*   ip = idx + h * KH;
    const float* wp = w   + h * KH;

    float ax = 0.f, ay = 0.f;
    #pragma unroll
    for (int k = 0; k < KH; ++k) {
        int   j  = __builtin_amdgcn_readfirstlane(ip[k]);
        float wk = wp[k];
        int jin  = (j < NUM_IN) ? j    : ZIN;            // scalar cselect
        int jhid = (j < NUM_IN) ? ZHID : (j - NUM_IN);   // scalar cselect
        const float2 v = *(const float2*)(in_f + (unsigned)jin * BATCH + 2 * lane);
        unsigned t = hid[(unsigned)jhid * 64 + lane];
        float sw = wk * INV255;
        ax = fmaf(wk, v.x, fmaf(sw, (float)(t & 0xFFu), ax));
        ay = fmaf(wk, v.y, fmaf(sw, (float)(t >> 8),   ay));
    }

    unsigned qx = __float2uint_rn(255.f / (1.f + __expf(-SCALEA * ax)));
    unsigned qy = __float2uint_rn(255.f / (1.f + __expf(-SCALEA * ay)));
    hid[(unsigned)(hbase + h) * 64 + lane] = (unsigned short)(qx | (qy << 8));
}

// Output layer: same dual-gather scheme, KO=64; f32 output out[b][o].
__global__ __launch_bounds__(256) void output_layer(const float* __restrict__ in_f,
                                                    const unsigned short* __restrict__ hid,
                                                    const int* __restrict__ idx,
                                                    const float* __restrict__ w,
                                                    float* __restrict__ out) {
    const int lane = threadIdx.x & 63;
    int o = (blockIdx.x << 2) + (threadIdx.x >> 6);
    o = __builtin_amdgcn_readfirstlane(o);
    const int*   ip = idx + o * KOUT;
    const float* wp = w   + o * KOUT;

    float ax = 0.f, ay = 0.f;
    #pragma unroll
    for (int k = 0; k < KOUT; ++k) {
        int   j  = __builtin_amdgcn_readfirstlane(ip[k]);
        float wk = wp[k];
        int jin  = (j < NUM_IN) ? j    : ZIN;
        int jhid = (j < NUM_IN) ? ZHID : (j - NUM_IN);
        const float2 v = *(const float2*)(in_f + (unsigned)jin * BATCH + 2 * lane);
        unsigned t = hid[(unsigned)jhid * 64 + lane];
        float sw = wk * INV255;
        ax = fmaf(wk, v.x, fmaf(sw, (float)(t & 0xFFu), ax));
        ay = fmaf(wk, v.y, fmaf(sw, (float)(t >> 8),   ay));
    }
    out[(2 * lane + 0) * OUTN + o] = 1.f / (1.f + __expf(-SCALEA * ax));
    out[(2 * lane + 1) * OUTN + o] = 1.f / (1.f + __expf(-SCALEA * ay));
}

extern "C" void kernel_launch(void* const* d_in, const int* in_sizes, int n_in,
                              void* d_out, int out_size, void* d_ws, size_t ws_size,
                              hipStream_t stream) {
    // setup_inputs() order: x, w_hidden, w_out, idx_hidden, idx_out
    const float* x          = (const float*)d_in[0];
    const float* w_hidden   = (const float*)d_in[1];
    const float* w_out      = (const float*)d_in[2];
    const int*   idx_hidden = (const int*)  d_in[3];
    const int*   idx_out    = (const int*)  d_in[4];
    float* out = (float*)d_out;

    char* ws = (char*)d_ws;
    float*          in_f = (float*)          (ws + 0);        // (4096+1)*128*4 = 2,097,664 B
    unsigned short* hid  = (unsigned short*) (ws + 2097664);  // (262144+1)*128 = 33,554,560 B

    transpose_x<<<NUM_IN / 64, 256, 0, stream>>>(x, in_f, hid);

    level0<<<HID / 4, 256, 0, stream>>>(in_f, hid, idx_hidden, w_hidden);
    for (int l = 1; l < LVL; ++l) {
        deep_level<<<HID / 4, 256, 0, stream>>>(
            in_f, hid,
            idx_hidden + (size_t)l * HID * KH,
            w_hidden   + (size_t)l * HID * KH,
            l * HID);
    }
    output_layer<<<OUTN / 4, 256, 0, stream>>>(in_f, hid, idx_out, w_out, out);
}

// Round 7
// 292.904 us; speedup vs baseline: 1.4178x; 1.4178x over previous
//
#include <hip/hip_runtime.h>

#define BATCH   128
#define NUM_IN  4096
#define LVL     8
#define HID     32768
#define KH      32
#define OUTN    256
#define KOUT    64
#define SCALEA  4.9f
#define INV255  (1.0f / 255.0f)
#define ZHID    (LVL * HID)   // zeroed dummy hidden node (hidden-relative)

// Workspace layout:
//   in_f @ 0         : f32 inputs node-major in_f[n*128+b]       2.0 MB (L2-resident)
//   hid  @ 2,097,152 : u8 hidden acts node-major, 128 B/node
//                      (64 ushorts, lane = batch pair); node ZHID = zero dummy
//
// R6 post-mortem: dual unconditional gathers doubled gather issue count
// (+14 us/level of L1/TA pipe time). This version: ONE u8 gather per entry
// (input entries -> zero dummy, scalar cselect, batchable like R5), plus a
// scalar-bitmask loop issuing f32 fix-up gathers ONLY for actual input
// entries (~2/unit, L2-resident source). Zero prep kernels.

__global__ __launch_bounds__(256) void transpose_x(const float* __restrict__ x,
                                                   float* __restrict__ in_f,
                                                   unsigned short* __restrict__ hid) {
    __shared__ float lds[64][129];
    const int n0 = blockIdx.x * 64;
    const int t  = threadIdx.x;
    #pragma unroll
    for (int it = 0; it < 32; ++it) {
        int i = it * 256 + t;
        int b = i >> 6;
        int n = i & 63;
        lds[n][b] = x[b * NUM_IN + n0 + n];
    }
    __syncthreads();
    #pragma unroll
    for (int it = 0; it < 32; ++it) {
        int i = it * 256 + t;
        int n = i >> 7;
        int b = i & 127;
        in_f[(n0 + n) * BATCH + b] = lds[n][b];
    }
    if (blockIdx.x == 0 && t < 64) hid[(unsigned)ZHID * 64 + t] = 0;  // zero dummy
}

// Level 0: all sources are inputs (randint maxval = NUM_IN). f32-only gathers.
__global__ __launch_bounds__(256) void level0(const float* __restrict__ in_f,
                                              unsigned short* __restrict__ hid,
                                              const int* __restrict__ idx,
                                              const float* __restrict__ w) {
    const int lane = threadIdx.x & 63;
    int h = (blockIdx.x << 2) + (threadIdx.x >> 6);
    h = __builtin_amdgcn_readfirstlane(h);
    const int*   ip = idx + h * KH;
    const float* wp = w   + h * KH;
    float ax = 0.f, ay = 0.f;
    #pragma unroll
    for (int k = 0; k < KH; ++k) {
        int   j  = __builtin_amdgcn_readfirstlane(ip[k]);
        float wk = wp[k];
        const float2 v = *(const float2*)(in_f + (unsigned)j * BATCH + 2 * lane);
        ax = fmaf(wk, v.x, ax);
        ay = fmaf(wk, v.y, ay);
    }
    unsigned qx = __float2uint_rn(255.f / (1.f + __expf(-SCALEA * ax)));
    unsigned qy = __float2uint_rn(255.f / (1.f + __expf(-SCALEA * ay)));
    hid[(unsigned)h * 64 + lane] = (unsigned short)(qx | (qy << 8));
}

// Levels 1..7: pass 1 = 32 branchless u8 gathers (input entries hit the zero
// dummy; scalar cselect only, loads stay batched) while building a scalar
// bitmask; pass 2 = scalar ctz loop over input entries (avg ~2), f32 gathers
// from the 2 MB L2-resident input buffer.
__global__ __launch_bounds__(256) void deep_level(const float* __restrict__ in_f,
                                                  unsigned short* __restrict__ hid,
                                                  const int* __restrict__ idx,
                                                  const float* __restrict__ w,
                                                  int hbase) {
    const int lane = threadIdx.x & 63;
    int h = (blockIdx.x << 2) + (threadIdx.x >> 6);
    h = __builtin_amdgcn_readfirstlane(h);
    const int*   ip = idx + h * KH;
    const float* wp = w   + h * KH;

    float ax = 0.f, ay = 0.f;
    unsigned mask = 0;                       // wave-uniform (SGPR) bitmask
    #pragma unroll
    for (int k = 0; k < KH; ++k) {
        int j = __builtin_amdgcn_readfirstlane(ip[k]);
        bool isin = (j < NUM_IN);
        mask |= (isin ? 1u : 0u) << k;                   // scalar or
        int jh = isin ? ZHID : (j - NUM_IN);             // scalar cselect
        unsigned t = hid[(unsigned)jh * 64 + lane];
        float sw = wp[k] * INV255;
        ax = fmaf(sw, (float)(t & 0xFFu), ax);
        ay = fmaf(sw, (float)(t >> 8),   ay);
    }
    mask = (unsigned)__builtin_amdgcn_readfirstlane((int)mask);
    while (mask) {                                       // uniform scalar loop
        int k = __builtin_ctz(mask);
        mask &= mask - 1u;
        int   j  = __builtin_amdgcn_readfirstlane(ip[k]);
        float wk = wp[k];
        const float2 v = *(const float2*)(in_f + (unsigned)j * BATCH + 2 * lane);
        ax = fmaf(wk, v.x, ax);
        ay = fmaf(wk, v.y, ay);
    }

    unsigned qx = __float2uint_rn(255.f / (1.f + __expf(-SCALEA * ax)));
    unsigned qy = __float2uint_rn(255.f / (1.f + __expf(-SCALEA * ay)));
    hid[(unsigned)(hbase + h) * 64 + lane] = (unsigned short)(qx | (qy << 8));
}

// Output layer: same scheme, KO=64 (64-bit mask); f32 output out[b][o].
__global__ __launch_bounds__(256) void output_layer(const float* __restrict__ in_f,
                                                    const unsigned short* __restrict__ hid,
                                                    const int* __restrict__ idx,
                                                    const float* __restrict__ w,
                                                    float* __restrict__ out) {
    const int lane = threadIdx.x & 63;
    int o = (blockIdx.x << 2) + (threadIdx.x >> 6);
    o = __builtin_amdgcn_readfirstlane(o);
    const int*   ip = idx + o * KOUT;
    const float* wp = w   + o * KOUT;

    float ax = 0.f, ay = 0.f;
    unsigned long long mask = 0ull;
    #pragma unroll
    for (int k = 0; k < KOUT; ++k) {
        int j = __builtin_amdgcn_readfirstlane(ip[k]);
        bool isin = (j < NUM_IN);
        mask |= (isin ? 1ull : 0ull) << k;
        int jh = isin ? ZHID : (j - NUM_IN);
        unsigned t = hid[(unsigned)jh * 64 + lane];
        float sw = wp[k] * INV255;
        ax = fmaf(sw, (float)(t & 0xFFu), ax);
        ay = fmaf(sw, (float)(t >> 8),   ay);
    }
    while (mask) {
        int k = __builtin_ctzll(mask);
        mask &= mask - 1ull;
        int   j  = __builtin_amdgcn_readfirstlane(ip[k]);
        float wk = wp[k];
        const float2 v = *(const float2*)(in_f + (unsigned)j * BATCH + 2 * lane);
        ax = fmaf(wk, v.x, ax);
        ay = fmaf(wk, v.y, ay);
    }
    out[(2 * lane + 0) * OUTN + o] = 1.f / (1.f + __expf(-SCALEA * ax));
    out[(2 * lane + 1) * OUTN + o] = 1.f / (1.f + __expf(-SCALEA * ay));
}

extern "C" void kernel_launch(void* const* d_in, const int* in_sizes, int n_in,
                              void* d_out, int out_size, void* d_ws, size_t ws_size,
                              hipStream_t stream) {
    // setup_inputs() order: x, w_hidden, w_out, idx_hidden, idx_out
    const float* x          = (const float*)d_in[0];
    const float* w_hidden   = (const float*)d_in[1];
    const float* w_out      = (const float*)d_in[2];
    const int*   idx_hidden = (const int*)  d_in[3];
    const int*   idx_out    = (const int*)  d_in[4];
    float* out = (float*)d_out;

    char* ws = (char*)d_ws;
    float*          in_f = (float*)          (ws + 0);        // 4096*128*4 = 2,097,152 B
    unsigned short* hid  = (unsigned short*) (ws + 2097152);  // (262144+1)*128 B

    transpose_x<<<NUM_IN / 64, 256, 0, stream>>>(x, in_f, hid);

    level0<<<HID / 4, 256, 0, stream>>>(in_f, hid, idx_hidden, w_hidden);
    for (int l = 1; l < LVL; ++l) {
        deep_level<<<HID / 4, 256, 0, stream>>>(
            in_f, hid,
            idx_hidden + (size_t)l * HID * KH,
            w_hidden   + (size_t)l * HID * KH,
            l * HID);
    }
    output_layer<<<OUTN / 4, 256, 0, stream>>>(in_f, hid, idx_out, w_out, out);
}

// Round 8
// 264.852 us; speedup vs baseline: 1.5680x; 1.1059x over previous
//
#include <hip/hip_runtime.h>

#define BATCH   128
#define NUM_IN  4096
#define LVL     8
#define HID     32768
#define KH      32
#define OUTN    256
#define KOUT    64
#define SCALEA  4.9f

// Input u8 affine quantization range [-QR, QR]
#define QR      6.0f
#define QSTEP   (2.0f * QR / 255.0f)   // dequant scale
#define INV255  (1.0f / 255.0f)

// Workspace layout:
//   in_bf @ 0         : bf16 inputs node-major, packed pairs (uint per lane):
//                       in_bf[n*64 + lane] = batch {2lane, 2lane+1}.  1.0 MB
//   ext   @ 1,048,576 : u8 acts for ALL nodes j in [0, 4096+8*32768):
//                       j<4096  -> affine-quantized input  x ~ u*QSTEP - QR
//                       j>=4096 -> sigmoid act             s ~ u/255
//                       ext[j*64+lane] = ushort batch pair. 34.1 MB
//
// R7 post-mortem: the serial ctz fix-up loop cost ~3 us/level; level0's f32
// 512B gathers doubled its line-touches. Now deep levels do ONE unconditional
// u8 gather per entry (no masks/dummies/fix-ups); input-vs-hidden only alters
// scalar dequant coefficients (s_cselect), never the load stream.

__device__ __forceinline__ unsigned short f2bf(float f) {
    unsigned u = __float_as_uint(f);
    u += 0x7FFFu + ((u >> 16) & 1u);   // round-to-nearest-even
    return (unsigned short)(u >> 16);
}
__device__ __forceinline__ float bf_lo(unsigned u) { return __uint_as_float(u << 16); }
__device__ __forceinline__ float bf_hi(unsigned u) { return __uint_as_float(u & 0xFFFF0000u); }

__device__ __forceinline__ unsigned q_in(float x) {   // input -> u8, range [-QR, QR]
    float t = (x + QR) * (255.0f / (2.0f * QR));
    t = fminf(fmaxf(t, 0.f), 255.f);
    return __float2uint_rn(t);
}

// ---------------------------------------------------------------------------
// Transpose x [B, NUM_IN] f32 -> in_bf (bf16 pairs) + ext[0..NUM_IN) (u8 pairs)
// ---------------------------------------------------------------------------
__global__ __launch_bounds__(256) void transpose_x(const float* __restrict__ x,
                                                   unsigned* __restrict__ in_bf,
                                                   unsigned short* __restrict__ ext) {
    __shared__ float lds[64][129];
    const int n0 = blockIdx.x * 64;
    const int t  = threadIdx.x;
    #pragma unroll
    for (int it = 0; it < 32; ++it) {
        int i = it * 256 + t;
        int b = i >> 6;
        int n = i & 63;
        lds[n][b] = x[b * NUM_IN + n0 + n];
    }
    __syncthreads();
    #pragma unroll
    for (int it = 0; it < 16; ++it) {
        int i  = it * 256 + t;      // 64 nodes x 64 batch-pairs
        int n  = i >> 6;
        int bp = i & 63;
        float v0 = lds[n][2 * bp], v1 = lds[n][2 * bp + 1];
        in_bf[(n0 + n) * 64 + bp] = (unsigned)f2bf(v0) | ((unsigned)f2bf(v1) << 16);
        ext[(unsigned)(n0 + n) * 64 + bp] =
            (unsigned short)(q_in(v0) | (q_in(v1) << 8));
    }
}

// ---------------------------------------------------------------------------
// Level 0: all sources are inputs (randint maxval = NUM_IN). bf16 gathers
// (256 B/node), full precision; writes u8 sigmoid acts into ext.
// ---------------------------------------------------------------------------
__global__ __launch_bounds__(256) void level0(const unsigned* __restrict__ in_bf,
                                              unsigned short* __restrict__ ext,
                                              const int* __restrict__ idx,
                                              const float* __restrict__ w) {
    const int lane = threadIdx.x & 63;
    int h = (blockIdx.x << 2) + (threadIdx.x >> 6);
    h = __builtin_amdgcn_readfirstlane(h);
    const int*   ip = idx + h * KH;
    const float* wp = w   + h * KH;
    float ax = 0.f, ay = 0.f;
    #pragma unroll
    for (int k = 0; k < KH; ++k) {
        int   j  = __builtin_amdgcn_readfirstlane(ip[k]);
        float wk = wp[k];
        unsigned v = in_bf[(unsigned)j * 64 + lane];
        ax = fmaf(wk, bf_lo(v), ax);
        ay = fmaf(wk, bf_hi(v), ay);
    }
    unsigned qx = __float2uint_rn(255.f / (1.f + __expf(-SCALEA * ax)));
    unsigned qy = __float2uint_rn(255.f / (1.f + __expf(-SCALEA * ay)));
    ext[(unsigned)(NUM_IN + h) * 64 + lane] = (unsigned short)(qx | (qy << 8));
}

// ---------------------------------------------------------------------------
// Levels 1..7: ONE unconditional u8 gather per entry from the uniform ext
// table. Input-vs-hidden selects only scalar dequant coeffs:
//   input : wk*x = wk*QSTEP*u - QR*wk   hidden: wk*s = (wk/255)*u
// ---------------------------------------------------------------------------
__global__ __launch_bounds__(256) void deep_level(unsigned short* __restrict__ ext,
                                                  const int* __restrict__ idx,
                                                  const float* __restrict__ w,
                                                  int nbase) {  // NUM_IN + l*HID
    const int lane = threadIdx.x & 63;
    int h = (blockIdx.x << 2) + (threadIdx.x >> 6);
    h = __builtin_amdgcn_readfirstlane(h);
    const int*   ip = idx + h * KH;
    const float* wp = w   + h * KH;

    float ax = 0.f, ay = 0.f, bias = 0.f;
    #pragma unroll
    for (int k = 0; k < KH; ++k) {
        int   j  = __builtin_amdgcn_readfirstlane(ip[k]);
        float wk = wp[k];
        bool isin = (j < NUM_IN);
        float a = wk * (isin ? QSTEP : INV255);   // scalar cselect
        bias   += isin ? (-QR * wk) : 0.f;        // scalar accumulate
        unsigned t = ext[(unsigned)j * 64 + lane];
        ax = fmaf(a, (float)(t & 0xFFu), ax);
        ay = fmaf(a, (float)(t >> 8),   ay);
    }
    ax += bias;
    ay += bias;

    unsigned qx = __float2uint_rn(255.f / (1.f + __expf(-SCALEA * ax)));
    unsigned qy = __float2uint_rn(255.f / (1.f + __expf(-SCALEA * ay)));
    ext[(unsigned)(nbase + h) * 64 + lane] = (unsigned short)(qx | (qy << 8));
}

// ---------------------------------------------------------------------------
// Output layer: same uniform-gather scheme, KO=64; f32 output out[b][o].
// ---------------------------------------------------------------------------
__global__ __launch_bounds__(256) void output_layer(const unsigned short* __restrict__ ext,
                                                    const int* __restrict__ idx,
                                                    const float* __restrict__ w,
                                                    float* __restrict__ out) {
    const int lane = threadIdx.x & 63;
    int o = (blockIdx.x << 2) + (threadIdx.x >> 6);
    o = __builtin_amdgcn_readfirstlane(o);
    const int*   ip = idx + o * KOUT;
    const float* wp = w   + o * KOUT;

    float ax = 0.f, ay = 0.f, bias = 0.f;
    #pragma unroll
    for (int k = 0; k < KOUT; ++k) {
        int   j  = __builtin_amdgcn_readfirstlane(ip[k]);
        float wk = wp[k];
        bool isin = (j < NUM_IN);
        float a = wk * (isin ? QSTEP : INV255);
        bias   += isin ? (-QR * wk) : 0.f;
        unsigned t = ext[(unsigned)j * 64 + lane];
        ax = fmaf(a, (float)(t & 0xFFu), ax);
        ay = fmaf(a, (float)(t >> 8),   ay);
    }
    ax += bias;
    ay += bias;
    out[(2 * lane + 0) * OUTN + o] = 1.f / (1.f + __expf(-SCALEA * ax));
    out[(2 * lane + 1) * OUTN + o] = 1.f / (1.f + __expf(-SCALEA * ay));
}

extern "C" void kernel_launch(void* const* d_in, const int* in_sizes, int n_in,
                              void* d_out, int out_size, void* d_ws, size_t ws_size,
                              hipStream_t stream) {
    // setup_inputs() order: x, w_hidden, w_out, idx_hidden, idx_out
    const float* x          = (const float*)d_in[0];
    const float* w_hidden   = (const float*)d_in[1];
    const float* w_out      = (const float*)d_in[2];
    const int*   idx_hidden = (const int*)  d_in[3];
    const int*   idx_out    = (const int*)  d_in[4];
    float* out = (float*)d_out;

    char* ws = (char*)d_ws;
    unsigned*       in_bf = (unsigned*)      (ws + 0);        // 4096*64*4   = 1,048,576 B
    unsigned short* ext   = (unsigned short*)(ws + 1048576);  // 266,240*128 = 34,078,720 B

    transpose_x<<<NUM_IN / 64, 256, 0, stream>>>(x, in_bf, ext);

    level0<<<HID / 4, 256, 0, stream>>>(in_bf, ext, idx_hidden, w_hidden);
    for (int l = 1; l < LVL; ++l) {
        deep_level<<<HID / 4, 256, 0, stream>>>(
            ext,
            idx_hidden + (size_t)l * HID * KH,
            w_hidden   + (size_t)l * HID * KH,
            NUM_IN + l * HID);
    }
    output_layer<<<OUTN / 4, 256, 0, stream>>>(ext, idx_out, w_out, out);
}